// Round 1
// baseline (2382.371 us; speedup 1.0000x reference)
//
#include <hip/hip_runtime.h>
#include <cstdint>
#include <cstddef>

#define DM   1024
#define DI   2048
#define DS   16
#define SEQ  2048
#define NB   4
#define NTOK (NB*SEQ)   // 8192

__device__ __forceinline__ float silu_f(float x){ return x / (1.f + __expf(-x)); }

// ---------------- fp32 tiled GEMM: 128x128 tile, BK=16, 256 thr, 8x8/thread ----
// C columns < split -> C0 (ld ldc0), >= split -> C1 (ld ldc1, col-split offset)
__global__ __launch_bounds__(256) void sgemm128(
    const float* __restrict__ A, const float* __restrict__ B,
    float* __restrict__ C0, float* __restrict__ C1,
    int M, int N, int K, int split, int ldc0, int ldc1)
{
  __shared__ float As[16][128];
  __shared__ float Bs[16][128];
  const int tid = threadIdx.x;
  const int bm = blockIdx.y * 128;
  const int bn = blockIdx.x * 128;
  const int tr = tid >> 4;   // 0..15
  const int tc = tid & 15;   // 0..15
  float acc[8][8];
  #pragma unroll
  for (int i = 0; i < 8; ++i)
    #pragma unroll
    for (int j = 0; j < 8; ++j) acc[i][j] = 0.f;

  for (int k0 = 0; k0 < K; k0 += 16) {
    // A tile: 128 rows x 16 k, transposed into As[k][m]
    #pragma unroll
    for (int l = 0; l < 2; ++l) {
      int idx = tid + l * 256;
      int row = idx >> 2;
      int c4  = (idx & 3) << 2;
      float4 v = *(const float4*)(A + (size_t)(bm + row) * K + k0 + c4);
      As[c4+0][row] = v.x; As[c4+1][row] = v.y; As[c4+2][row] = v.z; As[c4+3][row] = v.w;
    }
    // B tile: 16 k x 128 cols, row-major
    #pragma unroll
    for (int l = 0; l < 2; ++l) {
      int idx = tid + l * 256;
      int row = idx >> 5;
      int c4  = (idx & 31) << 2;
      *(float4*)(&Bs[row][c4]) = *(const float4*)(B + (size_t)(k0 + row) * N + bn + c4);
    }
    __syncthreads();
    #pragma unroll
    for (int k = 0; k < 16; ++k) {
      float a[8], b[8];
      *(float4*)(a)     = *(const float4*)(&As[k][tr*4]);
      *(float4*)(a + 4) = *(const float4*)(&As[k][tr*4 + 64]);
      *(float4*)(b)     = *(const float4*)(&Bs[k][tc*4]);
      *(float4*)(b + 4) = *(const float4*)(&Bs[k][tc*4 + 64]);
      #pragma unroll
      for (int i = 0; i < 8; ++i)
        #pragma unroll
        for (int j = 0; j < 8; ++j) acc[i][j] = fmaf(a[i], b[j], acc[i][j]);
    }
    __syncthreads();
  }
  // epilogue: whole 128-wide block lands on one side of split (split % 128 == 0)
  const bool left = (bn < split);
  float* Cp = left ? C0 : C1;
  const int ldc = left ? ldc0 : ldc1;
  const int cb  = bn - (left ? 0 : split) + tc * 4;
  #pragma unroll
  for (int i = 0; i < 8; ++i) {
    int row = bm + tr * 4 + ((i < 4) ? i : 60 + i);   // rows tr*4+{0..3} and +64
    float4 v0 = make_float4(acc[i][0], acc[i][1], acc[i][2], acc[i][3]);
    float4 v1 = make_float4(acc[i][4], acc[i][5], acc[i][6], acc[i][7]);
    *(float4*)(Cp + (size_t)row * ldc + cb)      = v0;
    *(float4*)(Cp + (size_t)row * ldc + cb + 64) = v1;
  }
}

// ---------------- causal depthwise conv(4) + silu ------------------------------
__global__ __launch_bounds__(256) void conv_silu_k(
    const float* __restrict__ xc, const float* __restrict__ cw, float* __restrict__ u)
{
  int idx = blockIdx.x * 256 + threadIdx.x;   // over NTOK*DI
  int c = idx & (DI - 1);
  int r = idx >> 11;          // token row
  int t = r & (SEQ - 1);      // position within batch
  float4 w = ((const float4*)cw)[c];          // conv_w[c,0,0..3]
  const float* base = xc + (size_t)r * DI + c;
  float acc = w.w * base[0];                  // k=3 -> in[t]
  if (t >= 1) acc += w.z * base[-1 * DI];
  if (t >= 2) acc += w.y * base[-2 * DI];
  if (t >= 3) acc += w.x * base[-3 * DI];
  u[idx] = silu_f(acc);
}

// ---------------- fused per-token projections: xp -> dt, Bp, ub ----------------
// 4 tokens per block to amortize weight reads (W_x 256KB, W_dt/W_Bp 128KB each)
__global__ __launch_bounds__(256) void token_proj(
    const float* __restrict__ u,     // [NTOK][DI]
    const float* __restrict__ W_x,   // [DI][32]
    const float* __restrict__ W_dt,  // [16][DI]
    const float* __restrict__ b_dt,  // [DI]
    const float* __restrict__ W_Bp,  // [16][DI]
    float* __restrict__ dt_out,      // [NTOK][DI]
    float* __restrict__ ub_out)      // [NTOK][DI]
{
  __shared__ float su[4][DI];        // 32 KB
  __shared__ float sxp[4][32];
  __shared__ float part[8][4][32];
  const int tid = threadIdx.x;
  const int r0 = blockIdx.x * 4;

  // stage 4 u rows (coalesced float4)
  const float4* u4 = (const float4*)(u + (size_t)r0 * DI);
  float4* s4 = (float4*)su;
  #pragma unroll
  for (int k = 0; k < 8; ++k) s4[tid + k * 256] = u4[tid + k * 256];
  __syncthreads();

  // xp[tok][j] = sum_c u[c] * W_x[c][j]; 8 c-groups x 32 j
  const int j = tid & 31, g = tid >> 5;
  #pragma unroll
  for (int tk = 0; tk < 4; ++tk) {
    const float* sur = su[tk];
    float s = 0.f;
    for (int c = g * 256; c < g * 256 + 256; ++c) s += sur[c] * W_x[c * 32 + j];
    part[g][tk][j] = s;
  }
  __syncthreads();
  if (tid < 128) {
    int tk = tid >> 5, jj = tid & 31;
    float s = 0.f;
    #pragma unroll
    for (int g2 = 0; g2 < 8; ++g2) s += part[g2][tk][jj];
    sxp[tk][jj] = s;
  }
  __syncthreads();

  // dt = clip(softplus(dt_raw @ W_dt + b_dt)); Bp = B_raw @ W_Bp; ub = u*Bp
  #pragma unroll
  for (int k = 0; k < 8; ++k) {
    int i = tid + k * 256;
    float wd[16], wb[16];
    #pragma unroll
    for (int s2 = 0; s2 < 16; ++s2) { wd[s2] = W_dt[s2 * DI + i]; wb[s2] = W_Bp[s2 * DI + i]; }
    const float bd = b_dt[i];
    #pragma unroll
    for (int tk = 0; tk < 4; ++tk) {
      float dd = bd, bp = 0.f;
      #pragma unroll
      for (int s2 = 0; s2 < 16; ++s2) {
        dd += sxp[tk][s2]      * wd[s2];
        bp += sxp[tk][16 + s2] * wb[s2];
      }
      float sp = (dd > 20.f) ? dd : log1pf(__expf(dd));     // softplus
      sp = fminf(fmaxf(sp, 1e-4f), 1.0f);                   // clip
      size_t off = (size_t)(r0 + tk) * DI + i;
      dt_out[off] = sp;
      ub_out[off] = su[tk][i] * bp;
    }
  }
}

// ---------------- sequential scan + epilogue -----------------------------------
// h_t = h_{t-1}*(1-dt) + ub ; y = (h + D*u) * silu(z)
// NOTE: y aliases dt buffer (read-before-write at identical index per thread):
// dt_ and y are deliberately NOT __restrict__.
__global__ __launch_bounds__(256) void scan_ep(
    const float* dt_, const float* __restrict__ ub, const float* __restrict__ u,
    const float* __restrict__ z, const float* __restrict__ Dp_, float* y)
{
  int gidx = blockIdx.x * 256 + threadIdx.x;   // 0..NB*DI-1
  int c = gidx & (DI - 1);
  int b = gidx >> 11;
  const float Dp = Dp_[c];
  size_t base = (size_t)b * SEQ * DI + c;
  float h = 0.f;
  #pragma unroll 4
  for (int t = 0; t < SEQ; ++t) {
    size_t off = base + (size_t)t * DI;
    float d   = dt_[off];
    float ubv = ub[off];
    float uv  = u[off];
    float zv  = z[off];
    h = h * (1.f - d) + ubv;
    y[off] = (h + Dp * uv) * silu_f(zv);
  }
}

extern "C" void kernel_launch(void* const* d_in, const int* in_sizes, int n_in,
                              void* d_out, int out_size, void* d_ws, size_t ws_size,
                              hipStream_t stream)
{
  const float* x     = (const float*)d_in[0];
  const float* W_in  = (const float*)d_in[1];
  const float* cw    = (const float*)d_in[2];
  const float* W_x   = (const float*)d_in[3];
  const float* W_dt  = (const float*)d_in[4];
  const float* b_dt  = (const float*)d_in[5];
  const float* W_Bp  = (const float*)d_in[6];
  const float* Dp    = (const float*)d_in[7];
  const float* W_out = (const float*)d_in[8];
  float* out = (float*)d_out;

  const size_t SZ = (size_t)NTOK * DI;        // 16.78M floats = 64 MiB
  float* w    = (float*)d_ws;
  float* bufA = w;             // xc -> dt -> y
  float* bufB = w + SZ;        // z
  float* bufC = w + 2 * SZ;    // u
  float* bufD = w + 3 * SZ;    // ub
  (void)ws_size; (void)in_sizes; (void)n_in; (void)out_size;

  // 1) xz = x @ W_in ; split into xc (bufA), z (bufB)
  sgemm128<<<dim3((2 * DI) / 128, NTOK / 128), 256, 0, stream>>>(
      x, W_in, bufA, bufB, NTOK, 2 * DI, DM, DI, DI, DI);

  // 2) u = silu(causal depthwise conv(xc))
  conv_silu_k<<<(NTOK * DI) / 256, 256, 0, stream>>>(bufA, cw, bufC);

  // 3) dt (bufA, overwrites dead xc), ub (bufD)
  token_proj<<<NTOK / 4, 256, 0, stream>>>(bufC, W_x, W_dt, b_dt, W_Bp, bufA, bufD);

  // 4) scan + (h + D*u)*silu(z) -> y (bufA, in-place over dt)
  scan_ep<<<(NB * DI) / 256, 256, 0, stream>>>(bufA, bufD, bufC, bufB, Dp, bufA);

  // 5) out = y @ W_out
  sgemm128<<<dim3(DM / 128, NTOK / 128), 256, 0, stream>>>(
      bufA, W_out, out, out, NTOK, DM, DI, DM, DM, DM);
}

// Round 4
// 1473.668 us; speedup vs baseline: 1.6166x; 1.6166x over previous
//
#include <hip/hip_runtime.h>
#include <cstdint>
#include <cstddef>

#define DM   1024
#define DI   2048
#define DS   16
#define SEQ  2048
#define NB   4
#define NTOK (NB*SEQ)   // 8192
#define CCH  32          // scan chunks per sequence
#define LC   (SEQ/CCH)   // 64 timesteps per chunk

__device__ __forceinline__ float silu_f(float x){ return x / (1.f + __expf(-x)); }

// ---------------- fp32 tiled GEMM: 128x128 tile, BK=16, 256 thr, 8x8/thread ----
__global__ __launch_bounds__(256) void sgemm128(
    const float* __restrict__ A, const float* __restrict__ B,
    float* __restrict__ C0, float* __restrict__ C1,
    int M, int N, int K, int split, int ldc0, int ldc1)
{
  __shared__ float As[16][128];
  __shared__ float Bs[16][128];
  const int tid = threadIdx.x;
  const int bm = blockIdx.y * 128;
  const int bn = blockIdx.x * 128;
  const int tr = tid >> 4;   // 0..15
  const int tc = tid & 15;   // 0..15
  float acc[8][8];
  #pragma unroll
  for (int i = 0; i < 8; ++i)
    #pragma unroll
    for (int j = 0; j < 8; ++j) acc[i][j] = 0.f;

  for (int k0 = 0; k0 < K; k0 += 16) {
    #pragma unroll
    for (int l = 0; l < 2; ++l) {
      int idx = tid + l * 256;
      int row = idx >> 2;
      int c4  = (idx & 3) << 2;
      float4 v = *(const float4*)(A + (size_t)(bm + row) * K + k0 + c4);
      As[c4+0][row] = v.x; As[c4+1][row] = v.y; As[c4+2][row] = v.z; As[c4+3][row] = v.w;
    }
    #pragma unroll
    for (int l = 0; l < 2; ++l) {
      int idx = tid + l * 256;
      int row = idx >> 5;
      int c4  = (idx & 31) << 2;
      *(float4*)(&Bs[row][c4]) = *(const float4*)(B + (size_t)(k0 + row) * N + bn + c4);
    }
    __syncthreads();
    #pragma unroll
    for (int k = 0; k < 16; ++k) {
      float a[8], b[8];
      *(float4*)(a)     = *(const float4*)(&As[k][tr*4]);
      *(float4*)(a + 4) = *(const float4*)(&As[k][tr*4 + 64]);
      *(float4*)(b)     = *(const float4*)(&Bs[k][tc*4]);
      *(float4*)(b + 4) = *(const float4*)(&Bs[k][tc*4 + 64]);
      #pragma unroll
      for (int i = 0; i < 8; ++i)
        #pragma unroll
        for (int j = 0; j < 8; ++j) acc[i][j] = fmaf(a[i], b[j], acc[i][j]);
    }
    __syncthreads();
  }
  const bool left = (bn < split);
  float* Cp = left ? C0 : C1;
  const int ldc = left ? ldc0 : ldc1;
  const int cb  = bn - (left ? 0 : split) + tc * 4;
  #pragma unroll
  for (int i = 0; i < 8; ++i) {
    int row = bm + tr * 4 + ((i < 4) ? i : 60 + i);
    float4 v0 = make_float4(acc[i][0], acc[i][1], acc[i][2], acc[i][3]);
    float4 v1 = make_float4(acc[i][4], acc[i][5], acc[i][6], acc[i][7]);
    *(float4*)(Cp + (size_t)row * ldc + cb)      = v0;
    *(float4*)(Cp + (size_t)row * ldc + cb + 64) = v1;
  }
}

// ---------------- causal depthwise conv(4) + silu ------------------------------
__global__ __launch_bounds__(256) void conv_silu_k(
    const float* __restrict__ xc, const float* __restrict__ cw, float* __restrict__ u)
{
  int idx = blockIdx.x * 256 + threadIdx.x;   // over NTOK*DI
  int c = idx & (DI - 1);
  int r = idx >> 11;          // token row
  int t = r & (SEQ - 1);      // position within batch
  float4 w = ((const float4*)cw)[c];          // conv_w[c,0,0..3]
  const float* base = xc + (size_t)r * DI + c;
  float acc = w.w * base[0];                  // k=3 -> in[t]
  if (t >= 1) acc += w.z * base[-1 * DI];
  if (t >= 2) acc += w.y * base[-2 * DI];
  if (t >= 3) acc += w.x * base[-3 * DI];
  u[idx] = silu_f(acc);
}

// ---------------- fused per-token projections: xp -> dt, Bp, ub ----------------
__global__ __launch_bounds__(256) void token_proj(
    const float* __restrict__ u,     // [NTOK][DI]
    const float* __restrict__ W_x,   // [DI][32]
    const float* __restrict__ W_dt,  // [16][DI]
    const float* __restrict__ b_dt,  // [DI]
    const float* __restrict__ W_Bp,  // [16][DI]
    float* __restrict__ dt_out,      // [NTOK][DI]
    float* __restrict__ ub_out)      // [NTOK][DI]
{
  __shared__ float su[4][DI];        // 32 KB
  __shared__ float sxp[4][32];
  __shared__ float part[8][4][32];
  const int tid = threadIdx.x;
  const int r0 = blockIdx.x * 4;

  const float4* u4 = (const float4*)(u + (size_t)r0 * DI);
  float4* s4 = (float4*)su;
  #pragma unroll
  for (int k = 0; k < 8; ++k) s4[tid + k * 256] = u4[tid + k * 256];
  __syncthreads();

  const int j = tid & 31, g = tid >> 5;
  #pragma unroll
  for (int tk = 0; tk < 4; ++tk) {
    const float* sur = su[tk];
    float s = 0.f;
    for (int c = g * 256; c < g * 256 + 256; ++c) s += sur[c] * W_x[c * 32 + j];
    part[g][tk][j] = s;
  }
  __syncthreads();
  if (tid < 128) {
    int tk = tid >> 5, jj = tid & 31;
    float s = 0.f;
    #pragma unroll
    for (int g2 = 0; g2 < 8; ++g2) s += part[g2][tk][jj];
    sxp[tk][jj] = s;
  }
  __syncthreads();

  #pragma unroll
  for (int k = 0; k < 8; ++k) {
    int i = tid + k * 256;
    float wd[16], wb[16];
    #pragma unroll
    for (int s2 = 0; s2 < 16; ++s2) { wd[s2] = W_dt[s2 * DI + i]; wb[s2] = W_Bp[s2 * DI + i]; }
    const float bd = b_dt[i];
    #pragma unroll
    for (int tk = 0; tk < 4; ++tk) {
      float dd = bd, bp = 0.f;
      #pragma unroll
      for (int s2 = 0; s2 < 16; ++s2) {
        dd += sxp[tk][s2]      * wd[s2];
        bp += sxp[tk][16 + s2] * wb[s2];
      }
      float sp = (dd > 20.f) ? dd : log1pf(__expf(dd));     // softplus
      sp = fminf(fmaxf(sp, 1e-4f), 1.0f);                   // clip
      size_t off = (size_t)(r0 + tk) * DI + i;
      dt_out[off] = sp;
      ub_out[off] = su[tk][i] * bp;
    }
  }
}

// ---------------- chunked parallel scan ----------------------------------------
// h_t = h_{t-1}*(1-dt_t) + ub_t  — linear recurrence, chunk-composable.
// Phase 1: per (b,chunk,di): P = prod(1-dt), S = local scan end value (h_in=0)
__global__ __launch_bounds__(256) void scan_p1(
    const float* __restrict__ dt_, const float* __restrict__ ub,
    float* __restrict__ P, float* __restrict__ S)
{
  int idx = blockIdx.x * 256 + threadIdx.x;   // over NB*CCH*DI
  int di = idx & (DI - 1);
  int bc = idx >> 11;          // b*CCH + c
  int c  = bc & (CCH - 1);
  int b  = bc >> 5;            // log2(CCH)=5
  size_t base = ((size_t)b * SEQ + (size_t)c * LC) * DI + di;
  float p = 1.f, s = 0.f;
  #pragma unroll 4
  for (int t = 0; t < LC; ++t) {
    size_t off = base + (size_t)t * DI;
    float a = 1.f - dt_[off];
    s = s * a + ub[off];
    p *= a;
  }
  P[idx] = p; S[idx] = s;
}

// Phase 2: serial compose over chunks -> incoming state per chunk
__global__ __launch_bounds__(256) void scan_p2(
    const float* __restrict__ P, const float* __restrict__ S, float* __restrict__ Hin)
{
  int idx = blockIdx.x * 256 + threadIdx.x;   // over NB*DI
  int di = idx & (DI - 1);
  int b  = idx >> 11;
  float h = 0.f;
  #pragma unroll
  for (int c = 0; c < CCH; ++c) {
    size_t off = ((size_t)b * CCH + c) * DI + di;
    Hin[off] = h;
    h = h * P[off] + S[off];
  }
}

// Phase 3: re-run chunk scan seeded with Hin, fused epilogue.
// y aliases dt_ (same-index read-before-write per thread) — no __restrict__.
__global__ __launch_bounds__(256) void scan_p3(
    const float* dt_, const float* __restrict__ ub, const float* __restrict__ u,
    const float* __restrict__ z, const float* __restrict__ Dp_,
    const float* __restrict__ Hin, float* y)
{
  int idx = blockIdx.x * 256 + threadIdx.x;   // over NB*CCH*DI
  int di = idx & (DI - 1);
  int bc = idx >> 11;
  int c  = bc & (CCH - 1);
  int b  = bc >> 5;
  const float Dp = Dp_[di];
  float h = Hin[idx];
  size_t base = ((size_t)b * SEQ + (size_t)c * LC) * DI + di;
  #pragma unroll 4
  for (int t = 0; t < LC; ++t) {
    size_t off = base + (size_t)t * DI;
    float d   = dt_[off];
    float ubv = ub[off];
    float uv  = u[off];
    float zv  = z[off];
    h = h * (1.f - d) + ubv;
    y[off] = (h + Dp * uv) * silu_f(zv);
  }
}

extern "C" void kernel_launch(void* const* d_in, const int* in_sizes, int n_in,
                              void* d_out, int out_size, void* d_ws, size_t ws_size,
                              hipStream_t stream)
{
  const float* x     = (const float*)d_in[0];
  const float* W_in  = (const float*)d_in[1];
  const float* cw    = (const float*)d_in[2];
  const float* W_x   = (const float*)d_in[3];
  const float* W_dt  = (const float*)d_in[4];
  const float* b_dt  = (const float*)d_in[5];
  const float* W_Bp  = (const float*)d_in[6];
  const float* Dp    = (const float*)d_in[7];
  const float* W_out = (const float*)d_in[8];
  float* out = (float*)d_out;

  const size_t SZ = (size_t)NTOK * DI;        // 16.78M floats = 64 MiB
  float* w    = (float*)d_ws;
  float* bufA = w;             // xc -> dt -> y
  float* bufB = w + SZ;        // z
  float* bufC = w + 2 * SZ;    // u
  float* bufD = w + 3 * SZ;    // ub
  // scan scratch lives in d_out (fully overwritten by the final GEMM)
  const size_t PS = (size_t)NB * CCH * DI;    // 262144 floats = 1 MiB
  float* Pbuf = out;
  float* Sbuf = out + PS;
  float* Hin  = out + 2 * PS;
  (void)ws_size; (void)in_sizes; (void)n_in; (void)out_size;

  // 1) xz = x @ W_in ; split into xc (bufA), z (bufB)
  sgemm128<<<dim3((2 * DI) / 128, NTOK / 128), 256, 0, stream>>>(
      x, W_in, bufA, bufB, NTOK, 2 * DI, DM, DI, DI, DI);

  // 2) u = silu(causal depthwise conv(xc))
  conv_silu_k<<<(NTOK * DI) / 256, 256, 0, stream>>>(bufA, cw, bufC);

  // 3) dt (bufA, overwrites dead xc), ub (bufD)
  token_proj<<<NTOK / 4, 256, 0, stream>>>(bufC, W_x, W_dt, b_dt, W_Bp, bufA, bufD);

  // 4) chunked scan + epilogue -> y (bufA, in-place over dt)
  scan_p1<<<(NB * CCH * DI) / 256, 256, 0, stream>>>(bufA, bufD, Pbuf, Sbuf);
  scan_p2<<<(NB * DI) / 256, 256, 0, stream>>>(Pbuf, Sbuf, Hin);
  scan_p3<<<(NB * CCH * DI) / 256, 256, 0, stream>>>(bufA, bufD, bufC, bufB, Dp, Hin, bufA);

  // 5) out = y @ W_out
  sgemm128<<<dim3(DM / 128, NTOK / 128), 256, 0, stream>>>(
      bufA, W_out, out, out, NTOK, DM, DI, DM, DM, DM);
}

// Round 5
// 553.372 us; speedup vs baseline: 4.3052x; 2.6631x over previous
//
#include <hip/hip_runtime.h>
#include <cstdint>
#include <cstddef>

#define DM   1024
#define DI   2048
#define DS   16
#define SEQ  2048
#define NB   4
#define NTOK (NB*SEQ)   // 8192
#define CCH  32          // scan chunks per sequence
#define LC   (SEQ/CCH)   // 64 timesteps per chunk

typedef __attribute__((ext_vector_type(8))) short short8v;
typedef __attribute__((ext_vector_type(4))) float f32x4;

__device__ __forceinline__ float silu_f(float x){ return x / (1.f + __expf(-x)); }

__device__ __forceinline__ unsigned short f2bf(float f){
  union { float f; unsigned u; } c; c.f = f;
  unsigned u = c.u + 0x7FFFu + ((c.u >> 16) & 1u);   // round-to-nearest-even
  return (unsigned short)(u >> 16);
}

// ---------------- bf16-MFMA GEMM: 128x128 tile, BK=32, 256 thr (4 waves 2x2) ---
// A,B fp32 in HBM; converted to bf16 (RNE) during reg-staging; fp32 accum.
// LDS fragment-major: frag[8][lane][8 bf16] -> conflict-free ds_read_b128.
// C columns < split -> C0 (ld ldc0), >= split -> C1 (col-split offset, ld ldc1)
__global__ __launch_bounds__(256) void mfma_gemm(
    const float* __restrict__ A, const float* __restrict__ B,
    float* __restrict__ C0, float* __restrict__ C1,
    int M, int N, int K, int split, int ldc0, int ldc1)
{
  __shared__ unsigned short Asm[8 * 64 * 8];   // 8 KiB
  __shared__ unsigned short Bsm[8 * 64 * 8];   // 8 KiB
  const int tid  = threadIdx.x;
  const int lane = tid & 63;
  const int w    = tid >> 6;       // wave 0..3
  const int wm   = w >> 1, wn = w & 1;
  const int bm = blockIdx.y * 128;
  const int bn = blockIdx.x * 128;

  f32x4 acc[4][4] = {};            // [m-frag][n-frag], 4 fp32/lane each

  // B staging: thread covers column n, k in [kh*16, kh*16+16)
  const int sn  = tid & 127;
  const int skh = tid >> 7;        // 0..1
  // A staging constants
  for (int k0 = 0; k0 < K; k0 += 32) {
    // ---- stage A: 128 rows x 32 k (coalesced float4 row reads) ----
    #pragma unroll
    for (int p = 0; p < 4; ++p) {
      int idx = tid + p * 256;
      int row = idx >> 3;          // 0..127
      int kc  = idx & 7;           // which float4 in the 32-k row
      float4 v = *(const float4*)(A + (size_t)(bm + row) * K + k0 + kc * 4);
      unsigned b0 = f2bf(v.x) | ((unsigned)f2bf(v.y) << 16);
      unsigned b1 = f2bf(v.z) | ((unsigned)f2bf(v.w) << 16);
      // dest: fm=row>>4, lane'=(kc>>1)*16+(row&15), j=(kc&1)*4  (ushort units)
      int off = (row >> 4) * 512 + (((kc >> 1) * 16 + (row & 15)) * 8) + (kc & 1) * 4;
      *(uint2*)(&Asm[off]) = make_uint2(b0, b1);
    }
    // ---- stage B: 32 k x 128 n (per-k wave-coalesced dword column reads) ----
    {
      const float* bp = B + (size_t)(k0 + skh * 16) * N + bn + sn;
      unsigned short bv[16];
      #pragma unroll
      for (int r = 0; r < 16; ++r) bv[r] = f2bf(bp[(size_t)r * N]);
      #pragma unroll
      for (int g = 0; g < 2; ++g) {
        int kg = skh * 2 + g;      // k-octet 0..3
        unsigned p0 = bv[g*8+0] | ((unsigned)bv[g*8+1] << 16);
        unsigned p1 = bv[g*8+2] | ((unsigned)bv[g*8+3] << 16);
        unsigned p2 = bv[g*8+4] | ((unsigned)bv[g*8+5] << 16);
        unsigned p3 = bv[g*8+6] | ((unsigned)bv[g*8+7] << 16);
        int off = (sn >> 4) * 512 + ((kg * 16 + (sn & 15)) * 8);
        *(uint4*)(&Bsm[off]) = make_uint4(p0, p1, p2, p3);
      }
    }
    __syncthreads();
    // ---- compute: 8 ds_read_b128 + 16 MFMA ----
    short8v afr[4], bfr[4];
    #pragma unroll
    for (int i = 0; i < 4; ++i) {
      afr[i] = *(const short8v*)(&Asm[(wm * 4 + i) * 512 + lane * 8]);
      bfr[i] = *(const short8v*)(&Bsm[(wn * 4 + i) * 512 + lane * 8]);
    }
    #pragma unroll
    for (int i = 0; i < 4; ++i)
      #pragma unroll
      for (int j = 0; j < 4; ++j)
        acc[i][j] = __builtin_amdgcn_mfma_f32_16x16x32_bf16(afr[i], bfr[j], acc[i][j], 0, 0, 0);
    __syncthreads();
  }

  // ---- epilogue: C row = (lane>>4)*4+reg, col = lane&15 (m89-verified) ----
  const bool left = (bn < split);
  float* Cp = left ? C0 : C1;
  const int ldc   = left ? ldc0 : ldc1;
  const int cbase = bn - (left ? 0 : split) + wn * 64 + (lane & 15);
  const int rbase = bm + wm * 64 + (lane >> 4) * 4;
  #pragma unroll
  for (int i = 0; i < 4; ++i)
    #pragma unroll
    for (int j = 0; j < 4; ++j) {
      int row0 = rbase + i * 16;
      int col  = cbase + j * 16;
      #pragma unroll
      for (int r = 0; r < 4; ++r)
        Cp[(size_t)(row0 + r) * ldc + col] = acc[i][j][r];
    }
}

// ---------------- causal depthwise conv(4) + silu ------------------------------
__global__ __launch_bounds__(256) void conv_silu_k(
    const float* __restrict__ xc, const float* __restrict__ cw, float* __restrict__ u)
{
  int idx = blockIdx.x * 256 + threadIdx.x;   // over NTOK*DI
  int c = idx & (DI - 1);
  int r = idx >> 11;          // token row
  int t = r & (SEQ - 1);      // position within batch
  float4 w = ((const float4*)cw)[c];          // conv_w[c,0,0..3]
  const float* base = xc + (size_t)r * DI + c;
  float acc = w.w * base[0];                  // k=3 -> in[t]
  if (t >= 1) acc += w.z * base[-1 * DI];
  if (t >= 2) acc += w.y * base[-2 * DI];
  if (t >= 3) acc += w.x * base[-3 * DI];
  u[idx] = silu_f(acc);
}

// ---------------- fused per-token projections: xp -> dt, Bp, ub ----------------
__global__ __launch_bounds__(256) void token_proj(
    const float* __restrict__ u,     // [NTOK][DI]
    const float* __restrict__ W_x,   // [DI][32]
    const float* __restrict__ W_dt,  // [16][DI]
    const float* __restrict__ b_dt,  // [DI]
    const float* __restrict__ W_Bp,  // [16][DI]
    float* __restrict__ dt_out,      // [NTOK][DI]
    float* __restrict__ ub_out)      // [NTOK][DI]
{
  __shared__ float su[4][DI];        // 32 KB
  __shared__ float sxp[4][32];
  __shared__ float part[8][4][32];
  const int tid = threadIdx.x;
  const int r0 = blockIdx.x * 4;

  const float4* u4 = (const float4*)(u + (size_t)r0 * DI);
  float4* s4 = (float4*)su;
  #pragma unroll
  for (int k = 0; k < 8; ++k) s4[tid + k * 256] = u4[tid + k * 256];
  __syncthreads();

  const int j = tid & 31, g = tid >> 5;
  #pragma unroll
  for (int tk = 0; tk < 4; ++tk) {
    const float* sur = su[tk];
    float s = 0.f;
    for (int c = g * 256; c < g * 256 + 256; ++c) s += sur[c] * W_x[c * 32 + j];
    part[g][tk][j] = s;
  }
  __syncthreads();
  if (tid < 128) {
    int tk = tid >> 5, jj = tid & 31;
    float s = 0.f;
    #pragma unroll
    for (int g2 = 0; g2 < 8; ++g2) s += part[g2][tk][jj];
    sxp[tk][jj] = s;
  }
  __syncthreads();

  #pragma unroll
  for (int k = 0; k < 8; ++k) {
    int i = tid + k * 256;
    float wd[16], wb[16];
    #pragma unroll
    for (int s2 = 0; s2 < 16; ++s2) { wd[s2] = W_dt[s2 * DI + i]; wb[s2] = W_Bp[s2 * DI + i]; }
    const float bd = b_dt[i];
    #pragma unroll
    for (int tk = 0; tk < 4; ++tk) {
      float dd = bd, bp = 0.f;
      #pragma unroll
      for (int s2 = 0; s2 < 16; ++s2) {
        dd += sxp[tk][s2]      * wd[s2];
        bp += sxp[tk][16 + s2] * wb[s2];
      }
      float sp = (dd > 20.f) ? dd : log1pf(__expf(dd));     // softplus
      sp = fminf(fmaxf(sp, 1e-4f), 1.0f);                   // clip
      size_t off = (size_t)(r0 + tk) * DI + i;
      dt_out[off] = sp;
      ub_out[off] = su[tk][i] * bp;
    }
  }
}

// ---------------- chunked parallel scan ----------------------------------------
// h_t = h_{t-1}*(1-dt_t) + ub_t  — linear recurrence, chunk-composable.
__global__ __launch_bounds__(256) void scan_p1(
    const float* __restrict__ dt_, const float* __restrict__ ub,
    float* __restrict__ P, float* __restrict__ S)
{
  int idx = blockIdx.x * 256 + threadIdx.x;   // over NB*CCH*DI
  int di = idx & (DI - 1);
  int bc = idx >> 11;          // b*CCH + c
  int c  = bc & (CCH - 1);
  int b  = bc >> 5;            // log2(CCH)=5
  size_t base = ((size_t)b * SEQ + (size_t)c * LC) * DI + di;
  float p = 1.f, s = 0.f;
  #pragma unroll 4
  for (int t = 0; t < LC; ++t) {
    size_t off = base + (size_t)t * DI;
    float a = 1.f - dt_[off];
    s = s * a + ub[off];
    p *= a;
  }
  P[idx] = p; S[idx] = s;
}

__global__ __launch_bounds__(256) void scan_p2(
    const float* __restrict__ P, const float* __restrict__ S, float* __restrict__ Hin)
{
  int idx = blockIdx.x * 256 + threadIdx.x;   // over NB*DI
  int di = idx & (DI - 1);
  int b  = idx >> 11;
  float h = 0.f;
  #pragma unroll
  for (int c = 0; c < CCH; ++c) {
    size_t off = ((size_t)b * CCH + c) * DI + di;
    Hin[off] = h;
    h = h * P[off] + S[off];
  }
}

// Phase 3: re-run chunk scan seeded with Hin, fused epilogue.
// y aliases dt_ (same-index read-before-write per thread) — no __restrict__.
__global__ __launch_bounds__(256) void scan_p3(
    const float* dt_, const float* __restrict__ ub, const float* __restrict__ u,
    const float* __restrict__ z, const float* __restrict__ Dp_,
    const float* __restrict__ Hin, float* y)
{
  int idx = blockIdx.x * 256 + threadIdx.x;   // over NB*CCH*DI
  int di = idx & (DI - 1);
  int bc = idx >> 11;
  int c  = bc & (CCH - 1);
  int b  = bc >> 5;
  const float Dp = Dp_[di];
  float h = Hin[idx];
  size_t base = ((size_t)b * SEQ + (size_t)c * LC) * DI + di;
  #pragma unroll 4
  for (int t = 0; t < LC; ++t) {
    size_t off = base + (size_t)t * DI;
    float d   = dt_[off];
    float ubv = ub[off];
    float uv  = u[off];
    float zv  = z[off];
    h = h * (1.f - d) + ubv;
    y[off] = (h + Dp * uv) * silu_f(zv);
  }
}

extern "C" void kernel_launch(void* const* d_in, const int* in_sizes, int n_in,
                              void* d_out, int out_size, void* d_ws, size_t ws_size,
                              hipStream_t stream)
{
  const float* x     = (const float*)d_in[0];
  const float* W_in  = (const float*)d_in[1];
  const float* cw    = (const float*)d_in[2];
  const float* W_x   = (const float*)d_in[3];
  const float* W_dt  = (const float*)d_in[4];
  const float* b_dt  = (const float*)d_in[5];
  const float* W_Bp  = (const float*)d_in[6];
  const float* Dp    = (const float*)d_in[7];
  const float* W_out = (const float*)d_in[8];
  float* out = (float*)d_out;

  const size_t SZ = (size_t)NTOK * DI;        // 16.78M floats = 64 MiB
  float* w    = (float*)d_ws;
  float* bufA = w;             // xc -> dt -> y
  float* bufB = w + SZ;        // z
  float* bufC = w + 2 * SZ;    // u
  float* bufD = w + 3 * SZ;    // ub
  // scan scratch lives in d_out (fully overwritten by the final GEMM)
  const size_t PS = (size_t)NB * CCH * DI;    // 262144 floats = 1 MiB
  float* Pbuf = out;
  float* Sbuf = out + PS;
  float* Hin  = out + 2 * PS;
  (void)ws_size; (void)in_sizes; (void)n_in; (void)out_size;

  // 1) xz = x @ W_in ; split into xc (bufA), z (bufB)   [bf16 MFMA]
  mfma_gemm<<<dim3((2 * DI) / 128, NTOK / 128), 256, 0, stream>>>(
      x, W_in, bufA, bufB, NTOK, 2 * DI, DM, DI, DI, DI);

  // 2) u = silu(causal depthwise conv(xc))
  conv_silu_k<<<(NTOK * DI) / 256, 256, 0, stream>>>(bufA, cw, bufC);

  // 3) dt (bufA, overwrites dead xc), ub (bufD)
  token_proj<<<NTOK / 4, 256, 0, stream>>>(bufC, W_x, W_dt, b_dt, W_Bp, bufA, bufD);

  // 4) chunked scan + epilogue -> y (bufA, in-place over dt)
  scan_p1<<<(NB * CCH * DI) / 256, 256, 0, stream>>>(bufA, bufD, Pbuf, Sbuf);
  scan_p2<<<(NB * DI) / 256, 256, 0, stream>>>(Pbuf, Sbuf, Hin);
  scan_p3<<<(NB * CCH * DI) / 256, 256, 0, stream>>>(bufA, bufD, bufC, bufB, Dp, Hin, bufA);

  // 5) out = y @ W_out   [bf16 MFMA]
  mfma_gemm<<<dim3(DM / 128, NTOK / 128), 256, 0, stream>>>(
      bufA, W_out, out, out, NTOK, DM, DI, DM, DM, DM);
}

// Round 6
// 399.956 us; speedup vs baseline: 5.9566x; 1.3836x over previous
//
#include <hip/hip_runtime.h>
#include <cstdint>
#include <cstddef>

#define DM   1024
#define DI   2048
#define SEQ  2048
#define NB   4
#define NTOK (NB*SEQ)   // 8192
#define CCH  32          // scan chunks per sequence
#define LC   (SEQ/CCH)   // 64 timesteps per chunk

typedef __attribute__((ext_vector_type(8))) short short8v;
typedef __attribute__((ext_vector_type(4))) float f32x4;
typedef unsigned short u16;
typedef unsigned int   u32;

__device__ __forceinline__ float silu_f(float x){ return x / (1.f + __expf(-x)); }

__device__ __forceinline__ u16 f2bf(float f){
  union { float f; u32 u; } c; c.f = f;
  u32 u = c.u + 0x7FFFu + ((c.u >> 16) & 1u);   // RNE
  return (u16)(u >> 16);
}
__device__ __forceinline__ float b2f(u16 b){
  union { u32 u; float f; } c; c.u = ((u32)b) << 16; return c.f;
}
__device__ __forceinline__ float lo2f(u32 v){ union { u32 u; float f; } c; c.u = v << 16; return c.f; }
__device__ __forceinline__ float hi2f(u32 v){ union { u32 u; float f; } c; c.u = v & 0xFFFF0000u; return c.f; }
__device__ __forceinline__ u32 pack2(float a, float b){ return (u32)f2bf(a) | ((u32)f2bf(b) << 16); }

__device__ __forceinline__ void gl16(const void* g, void* l){
  __builtin_amdgcn_global_load_lds((const __attribute__((address_space(1))) void*)g,
                                   (__attribute__((address_space(3))) void*)l, 16, 0, 0);
}

// ---------------- fp32 -> bf16 bulk convert --------------------------------
__global__ __launch_bounds__(256) void cvtk(const float4* __restrict__ in,
                                            u16* __restrict__ outp, int n4)
{
  int i = blockIdx.x * 256 + threadIdx.x;
  if (i < n4) {
    float4 v = in[i];
    *(uint2*)(outp + (size_t)i * 4) = make_uint2(pack2(v.x, v.y), pack2(v.z, v.w));
  }
}

// ---------------- fp32 [R][Cn] -> bf16 [Cn][R] transpose-convert -----------
__global__ __launch_bounds__(256) void transcvt(
    const float* __restrict__ W, u16* __restrict__ Wt, int R, int Cn)
{
  __shared__ float t[64][65];
  const int tid = threadIdx.x;
  const int bx = blockIdx.x, by = blockIdx.y;
  const int lr4 = tid >> 6;   // 0..3
  const int lc  = tid & 63;
  #pragma unroll
  for (int p = 0; p < 16; ++p) {
    int lr = p * 4 + lr4;
    t[lr][lc] = W[(size_t)(by * 64 + lr) * Cn + bx * 64 + lc];
  }
  __syncthreads();
  #pragma unroll
  for (int p = 0; p < 16; ++p) {
    int orr = p * 4 + lr4;
    Wt[(size_t)(bx * 64 + orr) * R + by * 64 + lc] = f2bf(t[lc][orr]);
  }
}

// ---------------- bf16 MFMA GEMM, m97 structure ----------------------------
// A [M][K] bf16, Bt [N][K] bf16 (B transposed). 128x128 tile, BK=32,
// 256 thr = 4 waves (2x2), global_load_lds width-16, linear LDS, fp32 acc.
// Output: cols < split -> C0, else C1 (both ld = ldc). OBF16 picks store type.
template<int OBF16>
__global__ __launch_bounds__(256) void gemm_bt(
    const u16* __restrict__ A, const u16* __restrict__ Bt,
    void* C0v, void* C1v, int M, int N, int K, int split, int ldc)
{
  __shared__ __align__(16) u16 Asm[128 * 32];
  __shared__ __align__(16) u16 Bsm[128 * 32];
  const int tid  = threadIdx.x;
  const int lane = tid & 63;
  const int w    = tid >> 6;
  const int wm   = w >> 1, wn = w & 1;
  const int bm = blockIdx.y * 128, bn = blockIdx.x * 128;

  f32x4 acc[4][4] = {};

  // staging: wave w covers tile rows [w*32, w*32+32); 2 issues of 16 rows each
  const int srow = w * 32 + (lane >> 2);
  const int soct = lane & 3;
  const u16* Ap = A  + (size_t)(bm + srow) * K + soct * 8;
  const u16* Bp = Bt + (size_t)(bn + srow) * K + soct * 8;
  u16* As0 = &Asm[w * 1024];
  u16* Bs0 = &Bsm[w * 1024];
  const size_t row16 = (size_t)16 * K;

  for (int k0 = 0; k0 < K; k0 += 32) {
    gl16(Ap + k0,         As0);
    gl16(Ap + k0 + row16, As0 + 512);
    gl16(Bp + k0,         Bs0);
    gl16(Bp + k0 + row16, Bs0 + 512);
    __syncthreads();          // compiler emits vmcnt(0) drain before barrier
    short8v afr[4], bfr[4];
    #pragma unroll
    for (int i = 0; i < 4; ++i) {
      afr[i] = *(const short8v*)&Asm[(wm * 64 + i * 16 + (lane & 15)) * 32 + (lane >> 4) * 8];
      bfr[i] = *(const short8v*)&Bsm[(wn * 64 + i * 16 + (lane & 15)) * 32 + (lane >> 4) * 8];
    }
    #pragma unroll
    for (int i = 0; i < 4; ++i)
      #pragma unroll
      for (int j = 0; j < 4; ++j)
        acc[i][j] = __builtin_amdgcn_mfma_f32_16x16x32_bf16(afr[i], bfr[j], acc[i][j], 0, 0, 0);
    __syncthreads();
  }

  // epilogue: C row = (lane>>4)*4 + r, col = lane&15 (verified in r5 kernel)
  const bool left = (bn < split);
  const int cb = bn - (left ? 0 : split) + wn * 64 + (lane & 15);
  const int rb = bm + wm * 64 + (lane >> 4) * 4;
  if (OBF16) {
    u16* Cp = (u16*)(left ? C0v : C1v);
    #pragma unroll
    for (int i = 0; i < 4; ++i)
      #pragma unroll
      for (int j = 0; j < 4; ++j)
        #pragma unroll
        for (int r = 0; r < 4; ++r)
          Cp[(size_t)(rb + i * 16 + r) * ldc + cb + j * 16] = f2bf(acc[i][j][r]);
  } else {
    float* Cp = (float*)(left ? C0v : C1v);
    #pragma unroll
    for (int i = 0; i < 4; ++i)
      #pragma unroll
      for (int j = 0; j < 4; ++j)
        #pragma unroll
        for (int r = 0; r < 4; ++r)
          Cp[(size_t)(rb + i * 16 + r) * ldc + cb + j * 16] = acc[i][j][r];
  }
}

// ---------------- causal depthwise conv(4) + silu, bf16 io, 2 ch/thread ----
__global__ __launch_bounds__(256) void conv_silu_k(
    const u16* __restrict__ xc, const float* __restrict__ cw, u16* __restrict__ u)
{
  int idx = blockIdx.x * 256 + threadIdx.x;   // over NTOK*DI/2
  int c = (idx & (DI / 2 - 1)) << 1;
  int r = idx >> 10;
  int t = r & (SEQ - 1);
  float4 w0 = ((const float4*)cw)[c];
  float4 w1 = ((const float4*)cw)[c + 1];
  const u16* base = xc + (size_t)r * DI + c;
  u32 v = *(const u32*)base;
  float a0 = w0.w * lo2f(v), a1 = w1.w * hi2f(v);
  if (t >= 1) { v = *(const u32*)(base - DI);     a0 += w0.z * lo2f(v); a1 += w1.z * hi2f(v); }
  if (t >= 2) { v = *(const u32*)(base - 2 * DI); a0 += w0.y * lo2f(v); a1 += w1.y * hi2f(v); }
  if (t >= 3) { v = *(const u32*)(base - 3 * DI); a0 += w0.x * lo2f(v); a1 += w1.x * hi2f(v); }
  *(u32*)(u + (size_t)r * DI + c) = pack2(silu_f(a0), silu_f(a1));
}

// ---------------- fused per-token projections: xp -> dt, Bp, ub ------------
__global__ __launch_bounds__(256) void token_proj(
    const u16* __restrict__ u,      // [NTOK][DI] bf16
    const float* __restrict__ W_x,  // [DI][32]
    const float* __restrict__ W_dt, // [16][DI]
    const float* __restrict__ b_dt, // [DI]
    const float* __restrict__ W_Bp, // [16][DI]
    u16* __restrict__ dt_out,       // [NTOK][DI] bf16
    u16* __restrict__ ub_out)       // [NTOK][DI] bf16
{
  __shared__ float su[4 * DI];      // 32 KB
  __shared__ float sxp[4][32];
  __shared__ float part[8][4][32];
  const int tid = threadIdx.x;
  const int r0 = blockIdx.x * 4;

  const short8v* u8 = (const short8v*)(u + (size_t)r0 * DI);
  #pragma unroll
  for (int k = 0; k < 4; ++k) {
    int e = tid + k * 256;          // 1024 short8s = 4*2048 elems
    short8v v = u8[e];
    #pragma unroll
    for (int jj = 0; jj < 8; ++jj) su[e * 8 + jj] = b2f((u16)v[jj]);
  }
  __syncthreads();

  const int j = tid & 31, g = tid >> 5;
  {
    float s0 = 0.f, s1 = 0.f, s2 = 0.f, s3 = 0.f;
    const float* wxp = W_x + j;
    for (int c = g * 256; c < g * 256 + 256; ++c) {
      float wv = wxp[c * 32];
      s0 += su[c] * wv;           s1 += su[DI + c] * wv;
      s2 += su[2 * DI + c] * wv;  s3 += su[3 * DI + c] * wv;
    }
    part[g][0][j] = s0; part[g][1][j] = s1; part[g][2][j] = s2; part[g][3][j] = s3;
  }
  __syncthreads();
  if (tid < 128) {
    int tk = tid >> 5, jj = tid & 31;
    float s = 0.f;
    #pragma unroll
    for (int g2 = 0; g2 < 8; ++g2) s += part[g2][tk][jj];
    sxp[tk][jj] = s;
  }
  __syncthreads();

  #pragma unroll
  for (int k = 0; k < 8; ++k) {
    int i = tid + k * 256;
    float wd[16], wb[16];
    #pragma unroll
    for (int s2 = 0; s2 < 16; ++s2) { wd[s2] = W_dt[s2 * DI + i]; wb[s2] = W_Bp[s2 * DI + i]; }
    const float bd = b_dt[i];
    #pragma unroll
    for (int tk = 0; tk < 4; ++tk) {
      float dd = bd, bp = 0.f;
      #pragma unroll
      for (int s2 = 0; s2 < 16; ++s2) {
        dd += sxp[tk][s2]      * wd[s2];
        bp += sxp[tk][16 + s2] * wb[s2];
      }
      float sp = (dd > 20.f) ? dd : log1pf(__expf(dd));     // softplus
      sp = fminf(fmaxf(sp, 1e-4f), 1.0f);                   // clip
      size_t off = (size_t)(r0 + tk) * DI + i;
      dt_out[off] = f2bf(sp);
      ub_out[off] = f2bf(su[tk * DI + i] * bp);
    }
  }
}

// ---------------- chunked parallel scan (bf16 in, 2 ch/thread) -------------
__global__ __launch_bounds__(256) void scan_p1(
    const u16* __restrict__ dt_, const u16* __restrict__ ub,
    float* __restrict__ P, float* __restrict__ S)
{
  int idx = blockIdx.x * 256 + threadIdx.x;   // NB*CCH*DI/2
  int di = (idx & (DI / 2 - 1)) << 1;
  int bc = idx >> 10;
  int c  = bc & (CCH - 1);
  int b  = bc >> 5;
  size_t base = ((size_t)b * SEQ + (size_t)c * LC) * DI + di;
  float p0 = 1.f, s0 = 0.f, p1 = 1.f, s1 = 0.f;
  #pragma unroll 4
  for (int t = 0; t < LC; ++t) {
    size_t off = base + (size_t)t * DI;
    u32 dv = *(const u32*)(dt_ + off);
    u32 uv = *(const u32*)(ub + off);
    float a0 = 1.f - lo2f(dv), a1 = 1.f - hi2f(dv);
    s0 = s0 * a0 + lo2f(uv); p0 *= a0;
    s1 = s1 * a1 + hi2f(uv); p1 *= a1;
  }
  ((float2*)P)[idx] = make_float2(p0, p1);
  ((float2*)S)[idx] = make_float2(s0, s1);
}

__global__ __launch_bounds__(256) void scan_p2(
    const float* __restrict__ P, const float* __restrict__ S, float* __restrict__ Hin)
{
  int idx = blockIdx.x * 256 + threadIdx.x;   // NB*DI
  int di = idx & (DI - 1);
  int b  = idx >> 11;
  float h = 0.f;
  #pragma unroll
  for (int c = 0; c < CCH; ++c) {
    size_t off = ((size_t)b * CCH + c) * DI + di;
    Hin[off] = h;
    h = h * P[off] + S[off];
  }
}

// Phase 3: chunk scan seeded with Hin + epilogue; writes y bf16 IN-PLACE over
// dt (same-thread same-index read-before-write) — dt_/y not __restrict__.
__global__ __launch_bounds__(256) void scan_p3(
    const u16* dt_, const u16* __restrict__ ub, const u16* __restrict__ u,
    const u16* __restrict__ z, const float* __restrict__ Dp_,
    const float* __restrict__ Hin, u16* y)
{
  int idx = blockIdx.x * 256 + threadIdx.x;   // NB*CCH*DI/2
  int di = (idx & (DI / 2 - 1)) << 1;
  int bc = idx >> 10;
  int c  = bc & (CCH - 1);
  int b  = bc >> 5;
  float2 dp = ((const float2*)Dp_)[di >> 1];
  float2 h2 = ((const float2*)Hin)[idx];
  float h0 = h2.x, h1 = h2.y;
  size_t base = ((size_t)b * SEQ + (size_t)c * LC) * DI + di;
  #pragma unroll 4
  for (int t = 0; t < LC; ++t) {
    size_t off = base + (size_t)t * DI;
    u32 dv = *(const u32*)(dt_ + off);
    u32 uv = *(const u32*)(ub + off);
    u32 uu = *(const u32*)(u + off);
    u32 zv = *(const u32*)(z + off);
    h0 = h0 * (1.f - lo2f(dv)) + lo2f(uv);
    h1 = h1 * (1.f - hi2f(dv)) + hi2f(uv);
    float y0 = (h0 + dp.x * lo2f(uu)) * silu_f(lo2f(zv));
    float y1 = (h1 + dp.y * hi2f(uu)) * silu_f(hi2f(zv));
    *(u32*)(y + off) = pack2(y0, y1);
  }
}

extern "C" void kernel_launch(void* const* d_in, const int* in_sizes, int n_in,
                              void* d_out, int out_size, void* d_ws, size_t ws_size,
                              hipStream_t stream)
{
  const float* x     = (const float*)d_in[0];
  const float* W_in  = (const float*)d_in[1];
  const float* cw    = (const float*)d_in[2];
  const float* W_x   = (const float*)d_in[3];
  const float* W_dt  = (const float*)d_in[4];
  const float* b_dt  = (const float*)d_in[5];
  const float* W_Bp  = (const float*)d_in[6];
  const float* Dp    = (const float*)d_in[7];
  const float* W_out = (const float*)d_in[8];
  float* out = (float*)d_out;

  const size_t SZ = (size_t)NTOK * DI;        // 16.78M floats per region
  float* w    = (float*)d_ws;
  float* bufA = w;
  float* bufB = w + SZ;
  float* bufC = w + 2 * SZ;
  float* bufD = w + 3 * SZ;

  u16* xcb  = (u16*)bufA;                     // xc bf16 -> dt bf16 -> y bf16
  u16* zb   = (u16*)bufB;                     // z bf16 [NTOK][DI]
  u16* wtob = zb + (size_t)NTOK * DI;         // Wt_out bf16 [DM][DI] (bufB tail)
  u16* xbf  = (u16*)bufC;                     // x bf16 [NTOK][DM]
  u16* wtib = xbf + (size_t)NTOK * DM;        // Wt_in bf16 [2DI][DM]
  u16* ubf  = (u16*)bufC;                     // u bf16 (overwrites xbf/wtib post-GEMM1)
  u16* ubb  = (u16*)bufD;                     // ub bf16

  const size_t PS = (size_t)NB * CCH * DI;    // 262144 floats
  float* Pbuf = out;                          // scan scratch in d_out
  float* Sbuf = out + PS;                     // (GEMM2 overwrites d_out fully)
  float* Hin  = out + 2 * PS;
  (void)ws_size; (void)in_sizes; (void)n_in; (void)out_size;

  // 0) one-shot conversions: x -> bf16; W_in, W_out -> transposed bf16
  cvtk<<<(NTOK * DM / 4) / 256, 256, 0, stream>>>((const float4*)x, xbf, NTOK * DM / 4);
  transcvt<<<dim3((2 * DI) / 64, DM / 64), 256, 0, stream>>>(W_in, wtib, DM, 2 * DI);
  transcvt<<<dim3(DM / 64, DI / 64), 256, 0, stream>>>(W_out, wtob, DI, DM);

  // 1) xz = x @ W_in -> xc (bf16, bufA), z (bf16, bufB)
  gemm_bt<1><<<dim3((2 * DI) / 128, NTOK / 128), 256, 0, stream>>>(
      xbf, wtib, (void*)xcb, (void*)zb, NTOK, 2 * DI, DM, DI, DI);

  // 2) u = silu(causal depthwise conv(xc))
  conv_silu_k<<<(NTOK * DI / 2) / 256, 256, 0, stream>>>(xcb, cw, ubf);

  // 3) dt (bufA, over dead xc), ub (bufD)
  token_proj<<<NTOK / 4, 256, 0, stream>>>(ubf, W_x, W_dt, b_dt, W_Bp, xcb, ubb);

  // 4) chunked scan + epilogue -> y bf16 (in place over dt)
  scan_p1<<<(NB * CCH * DI / 2) / 256, 256, 0, stream>>>(xcb, ubb, Pbuf, Sbuf);
  scan_p2<<<(NB * DI) / 256, 256, 0, stream>>>(Pbuf, Sbuf, Hin);
  scan_p3<<<(NB * CCH * DI / 2) / 256, 256, 0, stream>>>(xcb, ubb, ubf, zb, Dp, Hin, xcb);

  // 5) out = y @ W_out (fp32 out)
  gemm_bt<0><<<dim3(DM / 128, NTOK / 128), 256, 0, stream>>>(
      xcb, wtob, (void*)out, (void*)out, NTOK, DM, DI, DM, DM);
}